// Round 6
// baseline (182.405 us; speedup 1.0000x reference)
//
#include <hip/hip_runtime.h>

// Problem constants
#define D_B 8
#define N_T 2048
#define NN  64
#define N_H 8
#define N_C 32   // u-chunks of 64
#define NP  72   // padded LDS row stride (bf16): 144 B rows, 16B-aligned, 2-way alias (free)
#define MAGIC 0x1F2E3D4Cu

typedef __bf16 bf16;
typedef bf16 bf16x8 __attribute__((ext_vector_type(8)));
typedef bf16 bf16x4 __attribute__((ext_vector_type(4)));
typedef float f32x4 __attribute__((ext_vector_type(4)));

static __device__ __forceinline__ f32x4 mfma16(bf16x8 a, bf16x8 b, f32x4 c) {
    // a_frag[j] = A[lane&15][(lane>>4)*8+j]; b_frag[j] = B[(lane>>4)*8+j][lane&15]
    // d[r] = D[(lane>>4)*4+r][lane&15]
    return __builtin_amdgcn_mfma_f32_16x16x32_bf16(a, b, c, 0, 0, 0);
}

static __device__ __forceinline__ bf16x8 ldcvt8(const float* p) {
    const f32x4 v0 = *(const f32x4*)p;
    const f32x4 v1 = *(const f32x4*)(p + 4);
    bf16x8 r;
#pragma unroll
    for (int k = 0; k < 4; k++) { r[k] = (bf16)v0[k]; r[4 + k] = (bf16)v1[k]; }
    return r;
}

// ---------------------------------------------------------------------------
// SINGLE kernel (R6). Grid (D_B, N_C, 2) x 512 thr, 73.7 KB LDS -> exactly
// 2 blocks/CU -> ALL 512 blocks co-resident -> flag spin-wait cannot deadlock.
//
// PRODUCE (R5-proven k_dg, verbatim): two 4-wave groups, each the R3 2-head
// pipeline on its own LDS slab set; cross-group fp32 fold -> dGh (bf16,
// 2 partials/(b,c)) + diagh (fp32, 2 partials). Then __syncthreads (drains
// vmcnt) + threadfence + agent-scope flag publish per (b,c,zz).
//
// CONSUME (k_out folded in): wait for batch b's 64 flags (agent-scope atomic
// polls -> coherent; data loads safe: producer fence wrote back L2, and
// replay determinism makes stale reads value-identical). Then: 512-thread
// register scan of the 2 dGh streams (t<c, L2-hot) -> Gb (reused LDS);
// wave w = (quarter zz*2 + (w>>2), i-block w&3): 2 prefix MFMAs + fp32 diag
// fold + store. Launch boundary and k_out ramp eliminated; consume of batch
// b overlaps produce of other batches.
// ---------------------------------------------------------------------------
__global__ __launch_bounds__(512, 4) void k_all(
    const float* __restrict__ rp, const float* __restrict__ Qm,
    const float* __restrict__ Em,
    bf16* dGh, float* diagh, unsigned* flags, float* __restrict__ out)
{
    __shared__ __align__(16) char smem[2 * 4 * 64 * NP * 2];  // 73728 B
    const int b = blockIdx.x, c = blockIdx.y, zz = blockIdx.z;
    const int tid = threadIdx.x;
    const int g = tid >> 8, t8 = tid & 255;          // group, within-group tid
    bf16* Ql = (bf16*)smem + (size_t)g * 4 * 64 * NP;  // Q_h [i'][j]; later QT2 [u][i']
    bf16* El = Ql + 64 * NP;                           // E_h [i][j]; later S slabs
    bf16* QT = El + 64 * NP;                           // Qr [i'][u]; dG staging at tail
    bf16* ET = QT + 64 * NP;                           // Er [i][u]
    float* fst = (float*)Ql;                           // tail fp32 diag 64x66 (Ql+El)

    const int w = t8 >> 6, l = t8 & 63, q = l >> 4, l16 = l & 15;
    const int row = t8 >> 2, col = (t8 & 3) * 16;

    // ======================= PRODUCE (R5-proven) ===========================
    {
        // A-frags: r' rows u = t = c*64 + w*16 + l16 (shared by Qr/Er/S paths)
        const float* rrow = rp + ((size_t)b * N_T + c * 64 + w * 16 + l16) * NN;
        const bf16x8 a0 = ldcvt8(rrow + q * 8);
        const bf16x8 a1 = ldcvt8(rrow + 32 + q * 8);

        f32x4 dacc[4], acc[4];
#pragma unroll
        for (int ns = 0; ns < 4; ns++) {
            f32x4 z = {0.f, 0.f, 0.f, 0.f};
            dacc[ns] = z; acc[ns] = z;
        }

        for (int hh = 0; hh < 2; hh++) {
            const int h = zz * 4 + g * 2 + hh;
            {
                const float* qs = Qm + (size_t)h * 4096 + row * 64 + col;
                const float* es = Em + (size_t)h * 4096 + row * 64 + col;
                *(bf16x8*)&Ql[row * NP + col]     = ldcvt8(qs);
                *(bf16x8*)&Ql[row * NP + col + 8] = ldcvt8(qs + 8);
                *(bf16x8*)&El[row * NP + col]     = ldcvt8(es);
                *(bf16x8*)&El[row * NP + col + 8] = ldcvt8(es + 8);
            }
            __syncthreads();  // A: Ql/El ready
            bf16x4 pq[4];
#pragma unroll
            for (int ns = 0; ns < 4; ns++) {
                bf16x8 b0 = *(const bf16x8*)&Ql[(ns * 16 + l16) * NP + q * 8];
                bf16x8 b1 = *(const bf16x8*)&Ql[(ns * 16 + l16) * NP + 32 + q * 8];
                f32x4 z = {0.f, 0.f, 0.f, 0.f};
                f32x4 s = mfma16(a0, b0, z);
                s = mfma16(a1, b1, s);
                bf16x4 p;
#pragma unroll
                for (int r = 0; r < 4; r++) p[r] = (bf16)s[r];
                pq[ns] = p;
                *(bf16x4*)&QT[(ns * 16 + l16) * NP + w * 16 + q * 4] = p;  // [i'][u]
                b0 = *(const bf16x8*)&El[(ns * 16 + l16) * NP + q * 8];
                b1 = *(const bf16x8*)&El[(ns * 16 + l16) * NP + 32 + q * 8];
                f32x4 s2 = mfma16(a0, b0, z);
                s2 = mfma16(a1, b1, s2);
#pragma unroll
                for (int r = 0; r < 4; r++) p[r] = (bf16)s2[r];
                *(bf16x4*)&ET[(ns * 16 + l16) * NP + w * 16 + q * 4] = p;  // [i][u]
            }
            __syncthreads();  // B: QT/ET ready; Ql/El now dead
            {
                const bf16x8 qa0 = *(const bf16x8*)&QT[(w * 16 + l16) * NP + q * 8];
                const bf16x8 qa1 = *(const bf16x8*)&QT[(w * 16 + l16) * NP + 32 + q * 8];
#pragma unroll
                for (int ns = 0; ns < 4; ns++) {
                    const bf16x8 e0 = *(const bf16x8*)&ET[(ns * 16 + l16) * NP + q * 8];
                    const bf16x8 e1 = *(const bf16x8*)&ET[(ns * 16 + l16) * NP + 32 + q * 8];
                    dacc[ns] = mfma16(qa0, e0, dacc[ns]);
                    dacc[ns] = mfma16(qa1, e1, dacc[ns]);
                }
            }
#pragma unroll
            for (int ns = 0; ns < 4; ns++)
#pragma unroll
                for (int r = 0; r < 4; r++)
                    Ql[(w * 16 + q * 4 + r) * NP + ns * 16 + l16] = pq[ns][r];
            __syncthreads();  // C: QT2 (Ql) ready; El dead -> per-wave S slabs
            {
                bf16* Sw = El + (w * 16) * NP;   // this wave's 16-row slab
#pragma unroll
                for (int nu = 0; nu < 4; nu++) {
                    if (nu <= w) {
                        const bf16x8 b0 = *(const bf16x8*)&Ql[(nu * 16 + l16) * NP + q * 8];
                        const bf16x8 b1 = *(const bf16x8*)&Ql[(nu * 16 + l16) * NP + 32 + q * 8];
                        f32x4 z = {0.f, 0.f, 0.f, 0.f};
                        f32x4 sv = mfma16(a0, b0, z);
                        sv = mfma16(a1, b1, sv);
                        const int u_loc = nu * 16 + l16;
#pragma unroll
                        for (int r = 0; r < 4; r++) {
                            const int t_loc = w * 16 + q * 4 + r;
                            Sw[(q * 4 + r) * NP + u_loc] = (u_loc <= t_loc) ? (bf16)sv[r] : (bf16)0.f;
                        }
                    } else if ((w == 0 && nu == 1) || (w == 2 && nu == 3)) {
#pragma unroll
                        for (int r = 0; r < 4; r++)
                            Sw[(q * 4 + r) * NP + nu * 16 + l16] = (bf16)0.f;
                    }
                }
                const bf16x8 sa0 = *(const bf16x8*)&Sw[l16 * NP + q * 8];
#pragma unroll
                for (int ns = 0; ns < 4; ns++) {
                    const bf16x8 e0 = *(const bf16x8*)&ET[(ns * 16 + l16) * NP + q * 8];
                    acc[ns] = mfma16(sa0, e0, acc[ns]);
                }
                if (w >= 2) {
                    const bf16x8 sa1 = *(const bf16x8*)&Sw[l16 * NP + 32 + q * 8];
#pragma unroll
                    for (int ns = 0; ns < 4; ns++) {
                        const bf16x8 e1 = *(const bf16x8*)&ET[(ns * 16 + l16) * NP + 32 + q * 8];
                        acc[ns] = mfma16(sa1, e1, acc[ns]);
                    }
                }
            }
            __syncthreads();  // D: end of head
        }
        // tail: per-group stage dG (bf16 [i][i'] -> QT) and diag (fp32 -> fst)
#pragma unroll
        for (int ns = 0; ns < 4; ns++) {
            bf16x4 p;
#pragma unroll
            for (int r = 0; r < 4; r++) p[r] = (bf16)dacc[ns][r];
            *(bf16x4*)&QT[(ns * 16 + l16) * NP + w * 16 + q * 4] = p;
        }
#pragma unroll
        for (int ns = 0; ns < 4; ns++)
#pragma unroll
            for (int r = 0; r < 4; r++)
                fst[(w * 16 + q * 4 + r) * 66 + ns * 16 + l16] = acc[ns][r];
        __syncthreads();
        // cross-group fold (all 512 threads; 8 elems each) -> dGh, diagh
        {
            const int rr2 = tid >> 3, cc2 = (tid & 7) * 8;
            const bf16* QT0 = (const bf16*)smem + 2 * 64 * NP;
            const bf16* QT1 = (const bf16*)smem + 4 * 64 * NP + 2 * 64 * NP;
            const float* f0 = (const float*)smem;
            const float* f1 = (const float*)((const bf16*)smem + 4 * 64 * NP);
            const bf16x8 d0 = *(const bf16x8*)&QT0[rr2 * NP + cc2];
            const bf16x8 d1 = *(const bf16x8*)&QT1[rr2 * NP + cc2];
            bf16x8 o;
#pragma unroll
            for (int k = 0; k < 8; k++) o[k] = (bf16)((float)d0[k] + (float)d1[k]);
            const size_t tb = (((size_t)(b * N_C + c)) * 2 + zz) * 4096 + rr2 * 64 + cc2;
            *(bf16x8*)(dGh + tb) = o;
            float ds[8];
#pragma unroll
            for (int k = 0; k < 8; k++)
                ds[k] = f0[rr2 * 66 + cc2 + k] + f1[rr2 * 66 + cc2 + k];
            *(f32x4*)(diagh + tb)     = *(const f32x4*)&ds[0];
            *(f32x4*)(diagh + tb + 4) = *(const f32x4*)&ds[4];
        }
    }

    // ======================= PUBLISH =======================================
    __syncthreads();  // all global stores drained (vmcnt(0) before s_barrier)
    if (tid == 0) {
        __threadfence();  // write back L2 so other XCDs observe dGh/diagh
        atomicExch(&flags[(b * N_C + c) * 2 + zz], MAGIC);
    }

    // ======================= CONSUME (k_out folded in) =====================
    // wave wv -> quarter myq = zz*2 + (wv>>2), i-block ib = wv&3
    const int wv = tid >> 6, ln = tid & 63, q4 = ln >> 4, l16b = ln & 15;
    const int myq = zz * 2 + (wv >> 2), ib = wv & 3;

    // A-frags (input-only, hoisted above the wait): r' rows c*64+myq*16+l16b
    const float* rr = rp + ((size_t)b * N_T + c * 64 + myq * 16 + l16b) * NN;
    const bf16x8 ra0 = ldcvt8(rr + q4 * 8);
    const bf16x8 ra1 = ldcvt8(rr + 32 + q4 * 8);

    // wait for all 64 producer flags of batch b (agent-scope, L2-coherent)
    if (tid < 64) {
        const unsigned* fp = flags + b * 64 + tid;
        while (__hip_atomic_load(fp, __ATOMIC_RELAXED, __HIP_MEMORY_SCOPE_AGENT) != MAGIC)
            __builtin_amdgcn_s_sleep(2);
    }
    __threadfence();   // acquire: invalidate stale cache before data reads
    __syncthreads();

    // register scan of the 2 dGh streams for t<c (L2-hot), 8 elems/thread
    float run[8];
#pragma unroll
    for (int k = 0; k < 8; k++) run[k] = 0.f;
    {
        const bf16* base = dGh + (size_t)b * N_C * 2 * 4096 + tid * 8;
        int t = 0;
        for (; t + 2 <= c; t += 2) {
            bf16x8 v[4];
#pragma unroll
            for (int j = 0; j < 4; j++) {   // j = (t-offset<<1)|partial
                const size_t off = (size_t)((t + (j >> 1)) * 2 + (j & 1)) * 4096;
                v[j] = *(const bf16x8*)(base + off);
            }
#pragma unroll
            for (int j = 0; j < 4; j++)
#pragma unroll
                for (int k = 0; k < 8; k++) run[k] += (float)v[j][k];
        }
        for (; t < c; t++) {
#pragma unroll
            for (int p = 0; p < 2; p++) {
                const bf16x8 v0 = *(const bf16x8*)(base + (size_t)(t * 2 + p) * 4096);
#pragma unroll
                for (int k = 0; k < 8; k++) run[k] += (float)v0[k];
            }
        }
    }
    // Gb (reused LDS): Gcum [i][i'] bf16; elem idx = tid*8+k
    bf16* Gb = (bf16*)smem;
    {
        bf16x8 o;
#pragma unroll
        for (int k = 0; k < 8; k++) o[k] = (bf16)run[k];
        *(bf16x8*)&Gb[(tid >> 3) * NP + (tid & 7) * 8] = o;
    }
    // diag fold (fp32): 2 partials, wave's (quarter, i-block)
    float dsum[4];
#pragma unroll
    for (int r = 0; r < 4; r++) {
        const size_t di = (((size_t)(b * N_C + c)) * 2) * 4096 +
                          (myq * 16 + q4 * 4 + r) * 64 + ib * 16 + l16b;
        dsum[r] = diagh[di] + diagh[di + 4096];
    }
    __syncthreads();  // Gb ready
    f32x4 pacc = {0.f, 0.f, 0.f, 0.f};
    const bf16x8 g0 = *(const bf16x8*)&Gb[(ib * 16 + l16b) * NP + q4 * 8];
    const bf16x8 g1 = *(const bf16x8*)&Gb[(ib * 16 + l16b) * NP + 32 + q4 * 8];
    pacc = mfma16(ra0, g0, pacc);
    pacc = mfma16(ra1, g1, pacc);
#pragma unroll
    for (int r = 0; r < 4; r++)
        out[((size_t)b * N_T + c * 64 + myq * 16 + q4 * 4 + r) * NN + ib * 16 + l16b] =
            pacc[r] + dsum[r];
}

// ---------------------------------------------------------------------------
extern "C" void kernel_launch(void* const* d_in, const int* in_sizes, int n_in,
                              void* d_out, int out_size, void* d_ws, size_t ws_size,
                              hipStream_t stream) {
    const float* rp = (const float*)d_in[0];   // (8, 2048, 64) fp32
    const float* Qm = (const float*)d_in[1];   // (8, 64, 64)
    const float* Em = (const float*)d_in[2];   // (8, 64, 64)
    float* out = (float*)d_out;                // (8, 2048, 64) fp32

    // ws: dGh 4.2 MB (bf16) + diagh 8.4 MB (fp32) + flags 1 KB
    bf16* dGh = (bf16*)d_ws;
    float* diagh = (float*)(dGh + (size_t)D_B * N_C * 2 * 4096);
    unsigned* flags = (unsigned*)(diagh + (size_t)D_B * N_C * 2 * 4096);

    k_all<<<dim3(D_B, N_C, 2), 512, 0, stream>>>(rp, Qm, Em, dGh, diagh, flags, out);
}

// Round 7
// 97.571 us; speedup vs baseline: 1.8695x; 1.8695x over previous
//
#include <hip/hip_runtime.h>

// Problem constants
#define D_B 8
#define N_T 2048
#define NN  64
#define N_H 8
#define N_C 32   // u-chunks of 64
#define NP  72   // padded LDS row stride (bf16): 144 B rows, 16B-aligned, 2-way alias (free)
#define FSP 68   // fp32 diag staging row stride (floats): 272 B rows, 16B-aligned

typedef __bf16 bf16;
typedef bf16 bf16x8 __attribute__((ext_vector_type(8)));
typedef bf16 bf16x4 __attribute__((ext_vector_type(4)));
typedef float f32x4 __attribute__((ext_vector_type(4)));

static __device__ __forceinline__ f32x4 mfma16(bf16x8 a, bf16x8 b, f32x4 c) {
    // a_frag[j] = A[lane&15][(lane>>4)*8+j]; b_frag[j] = B[(lane>>4)*8+j][lane&15]
    // d[r] = D[(lane>>4)*4+r][lane&15]
    return __builtin_amdgcn_mfma_f32_16x16x32_bf16(a, b, c, 0, 0, 0);
}

static __device__ __forceinline__ bf16x8 ldcvt8(const float* p) {
    const f32x4 v0 = *(const f32x4*)p;
    const f32x4 v1 = *(const f32x4*)(p + 4);
    bf16x8 r;
#pragma unroll
    for (int k = 0; k < 4; k++) { r[k] = (bf16)v0[k]; r[4 + k] = (bf16)v1[k]; }
    return r;
}

// cvt 2 prefetched f32x4 regs -> bf16x8 (identical numerics to ldcvt8)
static __device__ __forceinline__ bf16x8 cvt8(const f32x4 v0, const f32x4 v1) {
    bf16x8 r;
#pragma unroll
    for (int k = 0; k < 4; k++) { r[k] = (bf16)v0[k]; r[4 + k] = (bf16)v1[k]; }
    return r;
}

// ---------------------------------------------------------------------------
// One head of the R5-proven k_dg pipeline, with T14 async-STAGE:
//   stage Ql/El from PRE-LOADED regs (no vmcnt on critical path), issue the
//   NEXT head's global loads (regs), then A;Qr/Er;B;dG+QT2;C;diag+PV;D.
// All MFMA fragment maps verbatim from the R3/R5-proven kernel.
// ---------------------------------------------------------------------------
template <bool LAST>
static __device__ __forceinline__ void head_body(
    bf16* __restrict__ Ql, bf16* __restrict__ El,
    bf16* __restrict__ QT, bf16* __restrict__ ET,
    const bf16x8 a0, const bf16x8 a1,
    const f32x4 (&qpre)[4], const f32x4 (&epre)[4],
    const float* qnext, const float* enext,
    f32x4 (&qpre2)[4], f32x4 (&epre2)[4],
    int w, int q, int l16, int row, int col,
    f32x4 (&dacc)[4], f32x4 (&acc)[4])
{
    // ---- stage from regs (pure cvt + ds_write)
    *(bf16x8*)&Ql[row * NP + col]     = cvt8(qpre[0], qpre[1]);
    *(bf16x8*)&Ql[row * NP + col + 8] = cvt8(qpre[2], qpre[3]);
    *(bf16x8*)&El[row * NP + col]     = cvt8(epre[0], epre[1]);
    *(bf16x8*)&El[row * NP + col + 8] = cvt8(epre[2], epre[3]);
    // ---- issue next head's loads (hidden under segments A..D)
    if (!LAST) {
        qpre2[0] = *(const f32x4*)qnext;       qpre2[1] = *(const f32x4*)(qnext + 4);
        qpre2[2] = *(const f32x4*)(qnext + 8); qpre2[3] = *(const f32x4*)(qnext + 12);
        epre2[0] = *(const f32x4*)enext;       epre2[1] = *(const f32x4*)(enext + 4);
        epre2[2] = *(const f32x4*)(enext + 8); epre2[3] = *(const f32x4*)(enext + 12);
    }
    __syncthreads();  // A: Ql/El ready
    // ---- Qr, Er for this wave's 16 u-rows; keep Qr bf16 in regs (pq)
    bf16x4 pq[4];
#pragma unroll
    for (int ns = 0; ns < 4; ns++) {
        bf16x8 b0 = *(const bf16x8*)&Ql[(ns * 16 + l16) * NP + q * 8];
        bf16x8 b1 = *(const bf16x8*)&Ql[(ns * 16 + l16) * NP + 32 + q * 8];
        f32x4 z = {0.f, 0.f, 0.f, 0.f};
        f32x4 s = mfma16(a0, b0, z);
        s = mfma16(a1, b1, s);
        bf16x4 p;
#pragma unroll
        for (int r = 0; r < 4; r++) p[r] = (bf16)s[r];
        pq[ns] = p;
        *(bf16x4*)&QT[(ns * 16 + l16) * NP + w * 16 + q * 4] = p;  // [i'][u]
        b0 = *(const bf16x8*)&El[(ns * 16 + l16) * NP + q * 8];
        b1 = *(const bf16x8*)&El[(ns * 16 + l16) * NP + 32 + q * 8];
        f32x4 s2 = mfma16(a0, b0, z);
        s2 = mfma16(a1, b1, s2);
#pragma unroll
        for (int r = 0; r < 4; r++) p[r] = (bf16)s2[r];
        *(bf16x4*)&ET[(ns * 16 + l16) * NP + w * 16 + q * 4] = p;  // [i][u]
    }
    __syncthreads();  // B: QT/ET ready; Ql/El now dead
    // ---- dG += Qr^T.Er; in parallel write QT2 [u][i'] -> Ql
    {
        const bf16x8 qa0 = *(const bf16x8*)&QT[(w * 16 + l16) * NP + q * 8];
        const bf16x8 qa1 = *(const bf16x8*)&QT[(w * 16 + l16) * NP + 32 + q * 8];
#pragma unroll
        for (int ns = 0; ns < 4; ns++) {
            const bf16x8 e0 = *(const bf16x8*)&ET[(ns * 16 + l16) * NP + q * 8];
            const bf16x8 e1 = *(const bf16x8*)&ET[(ns * 16 + l16) * NP + 32 + q * 8];
            dacc[ns] = mfma16(qa0, e0, dacc[ns]);
            dacc[ns] = mfma16(qa1, e1, dacc[ns]);
        }
    }
#pragma unroll
    for (int ns = 0; ns < 4; ns++)
#pragma unroll
        for (int r = 0; r < 4; r++)
            Ql[(w * 16 + q * 4 + r) * NP + ns * 16 + l16] = pq[ns][r];
    __syncthreads();  // C: QT2 (Ql) ready; El dead -> per-wave S slabs
    // ---- diag: S[t][u] = mask(r_t . Qr_u^T); only nu <= w nonzero
    {
        bf16* Sw = El + (w * 16) * NP;   // this wave's 16-row slab
#pragma unroll
        for (int nu = 0; nu < 4; nu++) {
            if (nu <= w) {
                const bf16x8 b0 = *(const bf16x8*)&Ql[(nu * 16 + l16) * NP + q * 8];
                const bf16x8 b1 = *(const bf16x8*)&Ql[(nu * 16 + l16) * NP + 32 + q * 8];
                f32x4 z = {0.f, 0.f, 0.f, 0.f};
                f32x4 sv = mfma16(a0, b0, z);
                sv = mfma16(a1, b1, sv);
                const int u_loc = nu * 16 + l16;
#pragma unroll
                for (int r = 0; r < 4; r++) {
                    const int t_loc = w * 16 + q * 4 + r;
                    Sw[(q * 4 + r) * NP + u_loc] = (u_loc <= t_loc) ? (bf16)sv[r] : (bf16)0.f;
                }
            } else if ((w == 0 && nu == 1) || (w == 2 && nu == 3)) {
#pragma unroll
                for (int r = 0; r < 4; r++)
                    Sw[(q * 4 + r) * NP + nu * 16 + l16] = (bf16)0.f;
            }
        }
        // same-wave in-order DS read-back; PV: acc += S.Er
        const bf16x8 sa0 = *(const bf16x8*)&Sw[l16 * NP + q * 8];
#pragma unroll
        for (int ns = 0; ns < 4; ns++) {
            const bf16x8 e0 = *(const bf16x8*)&ET[(ns * 16 + l16) * NP + q * 8];
            acc[ns] = mfma16(sa0, e0, acc[ns]);
        }
        if (w >= 2) {
            const bf16x8 sa1 = *(const bf16x8*)&Sw[l16 * NP + 32 + q * 8];
#pragma unroll
            for (int ns = 0; ns < 4; ns++) {
                const bf16x8 e1 = *(const bf16x8*)&ET[(ns * 16 + l16) * NP + 32 + q * 8];
                acc[ns] = mfma16(sa1, e1, acc[ns]);
            }
        }
    }
    __syncthreads();  // D: end of head (Ql/El/QT/ET reused next iter)
}

// ---------------------------------------------------------------------------
// K1 (R7 = R5 + T14): 512 threads = two independent 4-wave groups, each the
// proven 2-head pipeline on its own 36.9 KB LDS slab set; head Q/E tiles
// register-prefetched so the stage segment has no vmcnt wait. Cross-group
// fp32 fold -> dGh (bf16, 2 partials) + diagh (fp32, 2 partials).
// LDS 73.7 KB -> 2 blocks/CU = 16 waves/CU. Grid (D_B, N_C, 2): %8 = b.
// ---------------------------------------------------------------------------
__global__ __launch_bounds__(512, 4) void k_dg(
    const float* __restrict__ rp, const float* __restrict__ Qm,
    const float* __restrict__ Em,
    bf16* __restrict__ dGh, float* __restrict__ diagh)
{
    __shared__ __align__(16) char smem[2 * 4 * 64 * NP * 2];  // 73728 B
    const int b = blockIdx.x, c = blockIdx.y, zz = blockIdx.z;
    const int tid = threadIdx.x;
    const int g = tid >> 8, t8 = tid & 255;          // group, within-group tid
    bf16* Ql = (bf16*)smem + (size_t)g * 4 * 64 * NP;  // Q_h [i'][j]; later QT2 [u][i']
    bf16* El = Ql + 64 * NP;                           // E_h [i][j]; later S slabs
    bf16* QT = El + 64 * NP;                           // Qr [i'][u]; dG staging at tail
    bf16* ET = QT + 64 * NP;                           // Er [i][u]
    float* fst = (float*)Ql;                           // tail fp32 diag 64xFSP (Ql+El)

    const int w = t8 >> 6, l = t8 & 63, q = l >> 4, l16 = l & 15;
    const int row = t8 >> 2, col = (t8 & 3) * 16;

    // first head's Q/E prefetch + A-frag loads issue together
    const int h0 = zz * 4 + g * 2;
    const float* q0 = Qm + (size_t)h0 * 4096 + row * 64 + col;
    const float* e0 = Em + (size_t)h0 * 4096 + row * 64 + col;
    f32x4 qA[4], eA[4], qB[4], eB[4];
    qA[0] = *(const f32x4*)q0;       qA[1] = *(const f32x4*)(q0 + 4);
    qA[2] = *(const f32x4*)(q0 + 8); qA[3] = *(const f32x4*)(q0 + 12);
    eA[0] = *(const f32x4*)e0;       eA[1] = *(const f32x4*)(e0 + 4);
    eA[2] = *(const f32x4*)(e0 + 8); eA[3] = *(const f32x4*)(e0 + 12);

    // A-frags: r' rows u = t = c*64 + w*16 + l16 (shared by Qr/Er/S paths)
    const float* rrow = rp + ((size_t)b * N_T + c * 64 + w * 16 + l16) * NN;
    const bf16x8 a0 = ldcvt8(rrow + q * 8);
    const bf16x8 a1 = ldcvt8(rrow + 32 + q * 8);

    f32x4 dacc[4], acc[4];
#pragma unroll
    for (int ns = 0; ns < 4; ns++) {
        f32x4 z = {0.f, 0.f, 0.f, 0.f};
        dacc[ns] = z; acc[ns] = z;
    }

    head_body<false>(Ql, El, QT, ET, a0, a1, qA, eA,
                     q0 + 4096, e0 + 4096, qB, eB,
                     w, q, l16, row, col, dacc, acc);
    head_body<true>(Ql, El, QT, ET, a0, a1, qB, eB,
                    nullptr, nullptr, qA, eA,
                    w, q, l16, row, col, dacc, acc);

    // ---- tail: per-group stage dG (bf16 [i][i'] -> QT) and diag (fp32 -> fst)
#pragma unroll
    for (int ns = 0; ns < 4; ns++) {
        bf16x4 p;
#pragma unroll
        for (int r = 0; r < 4; r++) p[r] = (bf16)dacc[ns][r];
        *(bf16x4*)&QT[(ns * 16 + l16) * NP + w * 16 + q * 4] = p;
    }
#pragma unroll
    for (int ns = 0; ns < 4; ns++)
#pragma unroll
        for (int r = 0; r < 4; r++)
            fst[(w * 16 + q * 4 + r) * FSP + ns * 16 + l16] = acc[ns][r];
    __syncthreads();
    // ---- cross-group fold (all 512 threads; 8 elems each) -> dGh, diagh
    {
        const int rr2 = tid >> 3, cc2 = (tid & 7) * 8;
        const bf16* QT0 = (const bf16*)smem + 2 * 64 * NP;
        const bf16* QT1 = (const bf16*)smem + 4 * 64 * NP + 2 * 64 * NP;
        const float* f0 = (const float*)smem;
        const float* f1 = (const float*)((const bf16*)smem + 4 * 64 * NP);
        const bf16x8 d0 = *(const bf16x8*)&QT0[rr2 * NP + cc2];
        const bf16x8 d1 = *(const bf16x8*)&QT1[rr2 * NP + cc2];
        bf16x8 o;
#pragma unroll
        for (int k = 0; k < 8; k++) o[k] = (bf16)((float)d0[k] + (float)d1[k]);
        const size_t tb = (((size_t)(b * N_C + c)) * 2 + zz) * 4096 + rr2 * 64 + cc2;
        *(bf16x8*)(dGh + tb) = o;
        float ds[8];
#pragma unroll
        for (int k = 0; k < 8; k++)
            ds[k] = f0[rr2 * FSP + cc2 + k] + f1[rr2 * FSP + cc2 + k];
        *(f32x4*)(diagh + tb)     = *(const f32x4*)&ds[0];
        *(f32x4*)(diagh + tb + 4) = *(const f32x4*)&ds[4];
    }
}

// ---------------------------------------------------------------------------
// K2 (unchanged from R5): block (b, c, zz) -> out rows [c*64 + zz*16, +16).
// Register scan of the TWO dGh partial streams for t<c (L2-hot); wave w =
// i-block w: 2 prefix MFMAs; fp32 diag fold from the 2 diagh partials; store.
// 9 KB LDS. Grid (D_B, N_C, 4): linear%8 = b.
// ---------------------------------------------------------------------------
__global__ __launch_bounds__(256, 4) void k_out(
    const float* __restrict__ rp, const bf16* __restrict__ dGh,
    const float* __restrict__ diagh, float* __restrict__ out)
{
    __shared__ bf16 Gb[64 * NP];   // Gcum [i][i'] bf16
    const int b = blockIdx.x, c = blockIdx.y, zz = blockIdx.z;
    const int tid = threadIdx.x;
    const int w = tid >> 6, l = tid & 63, q = l >> 4, l16 = l & 15;

    // A-frags: r' rows t = c*64 + zz*16 + l16 (direct fp32, L2/L3-resident)
    const float* rr = rp + ((size_t)b * N_T + c * 64 + zz * 16 + l16) * NN;
    const bf16x8 ra0 = ldcvt8(rr + q * 8);
    const bf16x8 ra1 = ldcvt8(rr + 32 + q * 8);

    // diag fold (fp32): wave w owns i-block w; 2 partials
    float dsum[4];
#pragma unroll
    for (int r = 0; r < 4; r++) {
        const size_t di = (((size_t)(b * N_C + c)) * 2) * 4096 +
                          (zz * 16 + q * 4 + r) * 64 + w * 16 + l16;
        dsum[r] = diagh[di] + diagh[di + 4096];
    }

    // register scan of the 2 dGh streams for t<c (L2-hot), batch-2 over t
    float run[16];
#pragma unroll
    for (int k = 0; k < 16; k++) run[k] = 0.f;
    {
        const bf16* base = dGh + (size_t)b * N_C * 2 * 4096 + tid * 16;
        int t = 0;
        for (; t + 2 <= c; t += 2) {
            bf16x8 v[4][2];
#pragma unroll
            for (int j = 0; j < 4; j++) {   // j = (t-offset<<1)|partial
                const size_t off = (size_t)((t + (j >> 1)) * 2 + (j & 1)) * 4096;
                v[j][0] = *(const bf16x8*)(base + off);
                v[j][1] = *(const bf16x8*)(base + off + 8);
            }
#pragma unroll
            for (int j = 0; j < 4; j++)
#pragma unroll
                for (int k = 0; k < 8; k++) {
                    run[k] += (float)v[j][0][k];
                    run[8 + k] += (float)v[j][1][k];
                }
        }
        for (; t < c; t++) {
#pragma unroll
            for (int p = 0; p < 2; p++) {
                const size_t off = (size_t)(t * 2 + p) * 4096;
                const bf16x8 v0 = *(const bf16x8*)(base + off);
                const bf16x8 v1 = *(const bf16x8*)(base + off + 8);
#pragma unroll
                for (int k = 0; k < 8; k++) { run[k] += (float)v0[k]; run[8 + k] += (float)v1[k]; }
            }
        }
    }
    {
        bf16x8 o0, o1;
#pragma unroll
        for (int k = 0; k < 8; k++) { o0[k] = (bf16)run[k]; o1[k] = (bf16)run[8 + k]; }
        *(bf16x8*)&Gb[(tid >> 2) * NP + (tid & 3) * 16]     = o0;
        *(bf16x8*)&Gb[(tid >> 2) * NP + (tid & 3) * 16 + 8] = o1;
    }
    __syncthreads();  // Gb ready
    f32x4 pacc = {0.f, 0.f, 0.f, 0.f};
    const bf16x8 g0 = *(const bf16x8*)&Gb[(w * 16 + l16) * NP + q * 8];
    const bf16x8 g1 = *(const bf16x8*)&Gb[(w * 16 + l16) * NP + 32 + q * 8];
    pacc = mfma16(ra0, g0, pacc);
    pacc = mfma16(ra1, g1, pacc);
#pragma unroll
    for (int r = 0; r < 4; r++)
        out[((size_t)b * N_T + c * 64 + zz * 16 + q * 4 + r) * NN + w * 16 + l16] =
            pacc[r] + dsum[r];
}

// ---------------------------------------------------------------------------
extern "C" void kernel_launch(void* const* d_in, const int* in_sizes, int n_in,
                              void* d_out, int out_size, void* d_ws, size_t ws_size,
                              hipStream_t stream) {
    const float* rp = (const float*)d_in[0];   // (8, 2048, 64) fp32
    const float* Qm = (const float*)d_in[1];   // (8, 64, 64)
    const float* Em = (const float*)d_in[2];   // (8, 64, 64)
    float* out = (float*)d_out;                // (8, 2048, 64) fp32

    // ws: dGh 4.2 MB (bf16, 2 partials) + diagh 8.4 MB (fp32, 2 partials)
    bf16* dGh = (bf16*)d_ws;
    float* diagh = (float*)(dGh + (size_t)D_B * N_C * 2 * 4096);

    k_dg<<<dim3(D_B, N_C, 2), 512, 0, stream>>>(rp, Qm, Em, dGh, diagh);
    k_out<<<dim3(D_B, N_C, 4), 256, 0, stream>>>(rp, dGh, diagh, out);
}

// Round 8
// 88.797 us; speedup vs baseline: 2.0542x; 1.0988x over previous
//
#include <hip/hip_runtime.h>

// Problem constants
#define D_B 8
#define N_T 2048
#define NN  64
#define N_H 8
#define N_C 32   // u-chunks of 64
#define NP  72   // padded LDS row stride (bf16): 144 B rows, 16B-aligned, 2-way alias (free)
#define FSP 68   // fp32 diag staging row stride (floats): 272 B rows, 16B-aligned

typedef __bf16 bf16;
typedef bf16 bf16x8 __attribute__((ext_vector_type(8)));
typedef bf16 bf16x4 __attribute__((ext_vector_type(4)));
typedef float f32x4 __attribute__((ext_vector_type(4)));

static __device__ __forceinline__ f32x4 mfma16(bf16x8 a, bf16x8 b, f32x4 c) {
    // a_frag[j] = A[lane&15][(lane>>4)*8+j]; b_frag[j] = B[(lane>>4)*8+j][lane&15]
    // d[r] = D[(lane>>4)*4+r][lane&15]
    return __builtin_amdgcn_mfma_f32_16x16x32_bf16(a, b, c, 0, 0, 0);
}

static __device__ __forceinline__ bf16x8 ldcvt8(const float* p) {
    const f32x4 v0 = *(const f32x4*)p;
    const f32x4 v1 = *(const f32x4*)(p + 4);
    bf16x8 r;
#pragma unroll
    for (int k = 0; k < 4; k++) { r[k] = (bf16)v0[k]; r[4 + k] = (bf16)v1[k]; }
    return r;
}

// cvt 2 prefetched f32x4 regs -> bf16x8 (identical numerics to ldcvt8)
static __device__ __forceinline__ bf16x8 cvt8(const f32x4 v0, const f32x4 v1) {
    bf16x8 r;
#pragma unroll
    for (int k = 0; k < 4; k++) { r[k] = (bf16)v0[k]; r[4 + k] = (bf16)v1[k]; }
    return r;
}

// ---------------------------------------------------------------------------
// One head of the R5-proven k_dg pipeline, with T14 async-STAGE:
//   stage Ql/El from PRE-LOADED regs (no vmcnt on critical path), issue the
//   NEXT head's global loads (regs), then A;Qr/Er;B;dG+QT2;C;diag+PV;D.
// All MFMA fragment maps verbatim from the R3/R5-proven kernel.
// ---------------------------------------------------------------------------
template <bool LAST>
static __device__ __forceinline__ void head_body(
    bf16* __restrict__ Ql, bf16* __restrict__ El,
    bf16* __restrict__ QT, bf16* __restrict__ ET,
    const bf16x8 a0, const bf16x8 a1,
    const f32x4 (&qpre)[4], const f32x4 (&epre)[4],
    const float* qnext, const float* enext,
    f32x4 (&qpre2)[4], f32x4 (&epre2)[4],
    int w, int q, int l16, int row, int col,
    f32x4 (&dacc)[4], f32x4 (&acc)[4])
{
    // ---- stage from regs (pure cvt + ds_write)
    *(bf16x8*)&Ql[row * NP + col]     = cvt8(qpre[0], qpre[1]);
    *(bf16x8*)&Ql[row * NP + col + 8] = cvt8(qpre[2], qpre[3]);
    *(bf16x8*)&El[row * NP + col]     = cvt8(epre[0], epre[1]);
    *(bf16x8*)&El[row * NP + col + 8] = cvt8(epre[2], epre[3]);
    // ---- issue next head's loads (hidden under segments A..D)
    if (!LAST) {
        qpre2[0] = *(const f32x4*)qnext;       qpre2[1] = *(const f32x4*)(qnext + 4);
        qpre2[2] = *(const f32x4*)(qnext + 8); qpre2[3] = *(const f32x4*)(qnext + 12);
        epre2[0] = *(const f32x4*)enext;       epre2[1] = *(const f32x4*)(enext + 4);
        epre2[2] = *(const f32x4*)(enext + 8); epre2[3] = *(const f32x4*)(enext + 12);
    }
    __syncthreads();  // A: Ql/El ready
    // ---- Qr, Er for this wave's 16 u-rows; keep Qr bf16 in regs (pq)
    bf16x4 pq[4];
#pragma unroll
    for (int ns = 0; ns < 4; ns++) {
        bf16x8 b0 = *(const bf16x8*)&Ql[(ns * 16 + l16) * NP + q * 8];
        bf16x8 b1 = *(const bf16x8*)&Ql[(ns * 16 + l16) * NP + 32 + q * 8];
        f32x4 z = {0.f, 0.f, 0.f, 0.f};
        f32x4 s = mfma16(a0, b0, z);
        s = mfma16(a1, b1, s);
        bf16x4 p;
#pragma unroll
        for (int r = 0; r < 4; r++) p[r] = (bf16)s[r];
        pq[ns] = p;
        *(bf16x4*)&QT[(ns * 16 + l16) * NP + w * 16 + q * 4] = p;  // [i'][u]
        b0 = *(const bf16x8*)&El[(ns * 16 + l16) * NP + q * 8];
        b1 = *(const bf16x8*)&El[(ns * 16 + l16) * NP + 32 + q * 8];
        f32x4 s2 = mfma16(a0, b0, z);
        s2 = mfma16(a1, b1, s2);
#pragma unroll
        for (int r = 0; r < 4; r++) p[r] = (bf16)s2[r];
        *(bf16x4*)&ET[(ns * 16 + l16) * NP + w * 16 + q * 4] = p;  // [i][u]
    }
    __syncthreads();  // B: QT/ET ready; Ql/El now dead
    // ---- dG += Qr^T.Er; in parallel write QT2 [u][i'] -> Ql
    {
        const bf16x8 qa0 = *(const bf16x8*)&QT[(w * 16 + l16) * NP + q * 8];
        const bf16x8 qa1 = *(const bf16x8*)&QT[(w * 16 + l16) * NP + 32 + q * 8];
#pragma unroll
        for (int ns = 0; ns < 4; ns++) {
            const bf16x8 e0 = *(const bf16x8*)&ET[(ns * 16 + l16) * NP + q * 8];
            const bf16x8 e1 = *(const bf16x8*)&ET[(ns * 16 + l16) * NP + 32 + q * 8];
            dacc[ns] = mfma16(qa0, e0, dacc[ns]);
            dacc[ns] = mfma16(qa1, e1, dacc[ns]);
        }
    }
#pragma unroll
    for (int ns = 0; ns < 4; ns++)
#pragma unroll
        for (int r = 0; r < 4; r++)
            Ql[(w * 16 + q * 4 + r) * NP + ns * 16 + l16] = pq[ns][r];
    __syncthreads();  // C: QT2 (Ql) ready; El dead -> per-wave S slabs
    // ---- diag: S[t][u] = mask(r_t . Qr_u^T); only nu <= w nonzero
    {
        bf16* Sw = El + (w * 16) * NP;   // this wave's 16-row slab
#pragma unroll
        for (int nu = 0; nu < 4; nu++) {
            if (nu <= w) {
                const bf16x8 b0 = *(const bf16x8*)&Ql[(nu * 16 + l16) * NP + q * 8];
                const bf16x8 b1 = *(const bf16x8*)&Ql[(nu * 16 + l16) * NP + 32 + q * 8];
                f32x4 z = {0.f, 0.f, 0.f, 0.f};
                f32x4 sv = mfma16(a0, b0, z);
                sv = mfma16(a1, b1, sv);
                const int u_loc = nu * 16 + l16;
#pragma unroll
                for (int r = 0; r < 4; r++) {
                    const int t_loc = w * 16 + q * 4 + r;
                    Sw[(q * 4 + r) * NP + u_loc] = (u_loc <= t_loc) ? (bf16)sv[r] : (bf16)0.f;
                }
            } else if ((w == 0 && nu == 1) || (w == 2 && nu == 3)) {
#pragma unroll
                for (int r = 0; r < 4; r++)
                    Sw[(q * 4 + r) * NP + nu * 16 + l16] = (bf16)0.f;
            }
        }
        // same-wave in-order DS read-back; PV: acc += S.Er
        const bf16x8 sa0 = *(const bf16x8*)&Sw[l16 * NP + q * 8];
#pragma unroll
        for (int ns = 0; ns < 4; ns++) {
            const bf16x8 e0 = *(const bf16x8*)&ET[(ns * 16 + l16) * NP + q * 8];
            acc[ns] = mfma16(sa0, e0, acc[ns]);
        }
        if (w >= 2) {
            const bf16x8 sa1 = *(const bf16x8*)&Sw[l16 * NP + 32 + q * 8];
#pragma unroll
            for (int ns = 0; ns < 4; ns++) {
                const bf16x8 e1 = *(const bf16x8*)&ET[(ns * 16 + l16) * NP + 32 + q * 8];
                acc[ns] = mfma16(sa1, e1, acc[ns]);
            }
        }
    }
    __syncthreads();  // D: end of head (Ql/El/QT/ET reused next iter)
}

// ---------------------------------------------------------------------------
// K1 (unchanged from R7, proven 97.6): 512 threads = two independent 4-wave
// groups, each the proven 2-head pipeline on its own 36.9 KB LDS slab set;
// head Q/E tiles register-prefetched (T14). Cross-group fp32 fold -> dGh
// (bf16, 2 partials) + diagh (fp32, 2 partials). LDS 73.7 KB -> 2 blocks/CU.
// Grid (D_B, N_C, 2): linear%8 = b (XCD-local).
// ---------------------------------------------------------------------------
__global__ __launch_bounds__(512, 4) void k_dg(
    const float* __restrict__ rp, const float* __restrict__ Qm,
    const float* __restrict__ Em,
    bf16* __restrict__ dGh, float* __restrict__ diagh)
{
    __shared__ __align__(16) char smem[2 * 4 * 64 * NP * 2];  // 73728 B
    const int b = blockIdx.x, c = blockIdx.y, zz = blockIdx.z;
    const int tid = threadIdx.x;
    const int g = tid >> 8, t8 = tid & 255;          // group, within-group tid
    bf16* Ql = (bf16*)smem + (size_t)g * 4 * 64 * NP;  // Q_h [i'][j]; later QT2 [u][i']
    bf16* El = Ql + 64 * NP;                           // E_h [i][j]; later S slabs
    bf16* QT = El + 64 * NP;                           // Qr [i'][u]; dG staging at tail
    bf16* ET = QT + 64 * NP;                           // Er [i][u]
    float* fst = (float*)Ql;                           // tail fp32 diag 64xFSP (Ql+El)

    const int w = t8 >> 6, l = t8 & 63, q = l >> 4, l16 = l & 15;
    const int row = t8 >> 2, col = (t8 & 3) * 16;

    // first head's Q/E prefetch + A-frag loads issue together
    const int h0 = zz * 4 + g * 2;
    const float* q0 = Qm + (size_t)h0 * 4096 + row * 64 + col;
    const float* e0 = Em + (size_t)h0 * 4096 + row * 64 + col;
    f32x4 qA[4], eA[4], qB[4], eB[4];
    qA[0] = *(const f32x4*)q0;       qA[1] = *(const f32x4*)(q0 + 4);
    qA[2] = *(const f32x4*)(q0 + 8); qA[3] = *(const f32x4*)(q0 + 12);
    eA[0] = *(const f32x4*)e0;       eA[1] = *(const f32x4*)(e0 + 4);
    eA[2] = *(const f32x4*)(e0 + 8); eA[3] = *(const f32x4*)(e0 + 12);

    // A-frags: r' rows u = t = c*64 + w*16 + l16 (shared by Qr/Er/S paths)
    const float* rrow = rp + ((size_t)b * N_T + c * 64 + w * 16 + l16) * NN;
    const bf16x8 a0 = ldcvt8(rrow + q * 8);
    const bf16x8 a1 = ldcvt8(rrow + 32 + q * 8);

    f32x4 dacc[4], acc[4];
#pragma unroll
    for (int ns = 0; ns < 4; ns++) {
        f32x4 z = {0.f, 0.f, 0.f, 0.f};
        dacc[ns] = z; acc[ns] = z;
    }

    head_body<false>(Ql, El, QT, ET, a0, a1, qA, eA,
                     q0 + 4096, e0 + 4096, qB, eB,
                     w, q, l16, row, col, dacc, acc);
    head_body<true>(Ql, El, QT, ET, a0, a1, qB, eB,
                    nullptr, nullptr, qA, eA,
                    w, q, l16, row, col, dacc, acc);

    // ---- tail: per-group stage dG (bf16 [i][i'] -> QT) and diag (fp32 -> fst)
#pragma unroll
    for (int ns = 0; ns < 4; ns++) {
        bf16x4 p;
#pragma unroll
        for (int r = 0; r < 4; r++) p[r] = (bf16)dacc[ns][r];
        *(bf16x4*)&QT[(ns * 16 + l16) * NP + w * 16 + q * 4] = p;
    }
#pragma unroll
    for (int ns = 0; ns < 4; ns++)
#pragma unroll
        for (int r = 0; r < 4; r++)
            fst[(w * 16 + q * 4 + r) * FSP + ns * 16 + l16] = acc[ns][r];
    __syncthreads();
    // ---- cross-group fold (all 512 threads; 8 elems each) -> dGh, diagh
    {
        const int rr2 = tid >> 3, cc2 = (tid & 7) * 8;
        const bf16* QT0 = (const bf16*)smem + 2 * 64 * NP;
        const bf16* QT1 = (const bf16*)smem + 4 * 64 * NP + 2 * 64 * NP;
        const float* f0 = (const float*)smem;
        const float* f1 = (const float*)((const bf16*)smem + 4 * 64 * NP);
        const bf16x8 d0 = *(const bf16x8*)&QT0[rr2 * NP + cc2];
        const bf16x8 d1 = *(const bf16x8*)&QT1[rr2 * NP + cc2];
        bf16x8 o;
#pragma unroll
        for (int k = 0; k < 8; k++) o[k] = (bf16)((float)d0[k] + (float)d1[k]);
        const size_t tb = (((size_t)(b * N_C + c)) * 2 + zz) * 4096 + rr2 * 64 + cc2;
        *(bf16x8*)(dGh + tb) = o;
        float ds[8];
#pragma unroll
        for (int k = 0; k < 8; k++)
            ds[k] = f0[rr2 * FSP + cc2 + k] + f1[rr2 * FSP + cc2 + k];
        *(f32x4*)(diagh + tb)     = *(const f32x4*)&ds[0];
        *(f32x4*)(diagh + tb + 4) = *(const f32x4*)&ds[4];
    }
}

// ---------------------------------------------------------------------------
// K2 (R8): grid (D_B, N_C) x 1024 threads — the 4 zz quarters of a (b,c)
// SHARE one block, so the dGh prefix scan runs ONCE per (b,c) instead of 4x
// (aggregate L2 scan traffic 260 MB -> 65 MB; was brushing the 34.5 TB/s L2
// ceiling). Scan: 1024 threads x 4 elems (bf16x4), 8 loads in flight
// (4 t-steps x 2 partials) -> c/4-round latency chain. Epilogue per wave
// (R6-validated mapping): wave wv -> quarter wv>>2, i-block wv&3; 2 prefix
// MFMAs + fp32 diag fold + store. diag/A-frag loads hoisted above the scan.
// Per-element accumulation order unchanged -> bit-identical numerics.
// 9.2 KB LDS. Grid linear %8 = b (XCD-local).
// ---------------------------------------------------------------------------
__global__ __launch_bounds__(1024, 4) void k_out(
    const float* __restrict__ rp, const bf16* __restrict__ dGh,
    const float* __restrict__ diagh, float* __restrict__ out)
{
    __shared__ bf16 Gb[64 * NP];   // Gcum [i][i'] bf16
    const int b = blockIdx.x, c = blockIdx.y;
    const int tid = threadIdx.x;
    const int wv = tid >> 6, ln = tid & 63, q = ln >> 4, l16 = ln & 15;
    const int qq = wv >> 2, ib = wv & 3;   // quarter, i-block

    // A-frags (hoisted): r' rows t = c*64 + qq*16 + l16 (fp32, L2/L3-resident)
    const float* rr = rp + ((size_t)b * N_T + c * 64 + qq * 16 + l16) * NN;
    const bf16x8 ra0 = ldcvt8(rr + q * 8);
    const bf16x8 ra1 = ldcvt8(rr + 32 + q * 8);

    // diag fold (fp32, hoisted): wave (qq, ib); 2 partials
    float dsum[4];
#pragma unroll
    for (int r = 0; r < 4; r++) {
        const size_t di = (((size_t)(b * N_C + c)) * 2) * 4096 +
                          (qq * 16 + q * 4 + r) * 64 + ib * 16 + l16;
        dsum[r] = diagh[di] + diagh[di + 4096];
    }

    // register scan of the 2 dGh streams for t<c; 4 elems/thread, batch-8
    float run[4];
#pragma unroll
    for (int k = 0; k < 4; k++) run[k] = 0.f;
    {
        const bf16* base = dGh + (size_t)b * N_C * 2 * 4096 + tid * 4;
        int t = 0;
        for (; t + 4 <= c; t += 4) {
            bf16x4 v[8];
#pragma unroll
            for (int j = 0; j < 8; j++) {   // j = (t-offset<<1)|partial
                const size_t off = (size_t)((t + (j >> 1)) * 2 + (j & 1)) * 4096;
                v[j] = *(const bf16x4*)(base + off);
            }
#pragma unroll
            for (int j = 0; j < 8; j++)
#pragma unroll
                for (int k = 0; k < 4; k++) run[k] += (float)v[j][k];
        }
        for (; t < c; t++) {
#pragma unroll
            for (int p = 0; p < 2; p++) {
                const bf16x4 v0 = *(const bf16x4*)(base + (size_t)(t * 2 + p) * 4096);
#pragma unroll
                for (int k = 0; k < 4; k++) run[k] += (float)v0[k];
            }
        }
    }
    // Gb publish: elem e = tid*4+k -> row e>>6 = tid>>4, col (tid&15)*4 + k
    {
        bf16x4 o;
#pragma unroll
        for (int k = 0; k < 4; k++) o[k] = (bf16)run[k];
        *(bf16x4*)&Gb[(tid >> 4) * NP + (tid & 15) * 4] = o;
    }
    __syncthreads();  // Gb ready
    f32x4 pacc = {0.f, 0.f, 0.f, 0.f};
    const bf16x8 g0 = *(const bf16x8*)&Gb[(ib * 16 + l16) * NP + q * 8];
    const bf16x8 g1 = *(const bf16x8*)&Gb[(ib * 16 + l16) * NP + 32 + q * 8];
    pacc = mfma16(ra0, g0, pacc);
    pacc = mfma16(ra1, g1, pacc);
#pragma unroll
    for (int r = 0; r < 4; r++)
        out[((size_t)b * N_T + c * 64 + qq * 16 + q * 4 + r) * NN + ib * 16 + l16] =
            pacc[r] + dsum[r];
}

// ---------------------------------------------------------------------------
extern "C" void kernel_launch(void* const* d_in, const int* in_sizes, int n_in,
                              void* d_out, int out_size, void* d_ws, size_t ws_size,
                              hipStream_t stream) {
    const float* rp = (const float*)d_in[0];   // (8, 2048, 64) fp32
    const float* Qm = (const float*)d_in[1];   // (8, 64, 64)
    const float* Em = (const float*)d_in[2];   // (8, 64, 64)
    float* out = (float*)d_out;                // (8, 2048, 64) fp32

    // ws: dGh 4.2 MB (bf16, 2 partials) + diagh 8.4 MB (fp32, 2 partials)
    bf16* dGh = (bf16*)d_ws;
    float* diagh = (float*)(dGh + (size_t)D_B * N_C * 2 * 4096);

    k_dg<<<dim3(D_B, N_C, 2), 512, 0, stream>>>(rp, Qm, Em, dGh, diagh);
    k_out<<<dim3(D_B, N_C), 1024, 0, stream>>>(rp, dGh, diagh, out);
}